// Round 6
// baseline (20.831 us; speedup 1.0000x reference)
//
#include <hip/hip_runtime.h>
#include <math.h>

// VoronoiDecoder: N=65536 x S=32. 8 lanes/point, 4 seeds/lane, 256-thr blocks,
// 32 points/block, grid=2048 exact. Pair sigmoids split across pipes:
// 22 via LDS table (6 in-lane + r=1 rotation), 48 via exp2+rcp (r=2,3,4) --
// balances the per-CU DS pipe (R5 bottleneck) against per-SIMD trans pipe.
// No launch_bounds VGPR cap (R4's spill trap). Runtime-sized table (~1.2K
// entries), clamped reads land in the naturally-tiny tail.

#define LOG2E   1.4426950408889634f
#define EPSF    1e-8f
#define TSCALE  4096.0f          // distance units per 1.0
#define TAB_MAX 2820             // static bound: ceil(0.684*4096)+pad
#define BLOCK   256
#define PPB     32               // points per block
#define SSTR    40               // slab row stride (words): 2-way banks = free

__global__ __launch_bounds__(BLOCK) void voronoi_v6(
    const float* __restrict__ points,   // (N,2)
    const float* __restrict__ seeds,    // (32,2)
    const float* __restrict__ w_raw,    // (1,)
    const float* __restrict__ theta,    // (32,)
    const float* __restrict__ a_raw,    // (32,)
    float* __restrict__ out,            // (N,)
    int N)
{
    __shared__ float s_tab[TAB_MAX];
    __shared__ float s_dd[PPB * SSTR];
    __shared__ float s_ww[PPB * SSTR];
    __shared__ float s_su[32], s_sv[32], s_m00[32], s_m01[32], s_m11[32];

    const int t = threadIdx.x;

    // uniform band half-width
    const float wr = w_raw[0];
    const float sg = __builtin_amdgcn_rcpf(1.0f + exp2f(wr * (-LOG2E / 5.0f)));
    const float w  = 0.005f + 0.495f * sg;

    // table extent: sigma((w-K/T)/beta) < 1e-4 beyond K; clamp reads there
    const int K   = (int)(w * TSCALE + 0.19f * TSCALE) + 2;   // <= 2806
    const int KB4 = K * 4;

    // seed metrics, pre-scaled so sqrt lands in table units (2x folded in m01)
    if (t < 32) {
        const float x  = a_raw[t];
        const float z  = exp2f(2.0f * LOG2E * x);
        const float th = (z - 1.0f) * __builtin_amdgcn_rcpf(z + 1.0f);  // tanh
        const float a  = 0.75f * th + 1.25f;
        const float ia = __builtin_amdgcn_rcpf(a + EPSF);
        const float cs = __cosf(theta[t]);
        const float sn = __sinf(theta[t]);
        const float S2 = TSCALE * TSCALE;
        s_m00[t] = (a * cs * cs + ia * sn * sn) * S2;
        s_m01[t] = (2.0f * cs * sn * (ia - a)) * S2;
        s_m11[t] = (a * sn * sn + ia * cs * cs) * S2;
        s_su[t]  = seeds[2 * t];
        s_sv[t]  = seeds[2 * t + 1];
    }
    // band table: T[k] = sigmoid((w - k/TSCALE)/0.02), k in [0, K+3]
    {
        const float kC = (50.0f * LOG2E) / TSCALE;
        const float kB = -w * (50.0f * LOG2E);
        for (int k = t; k < K + 4; k += BLOCK) {
            const float y = exp2f(fmaf((float)k, kC, kB));
            s_tab[k] = __builtin_amdgcn_rcpf(1.0f + y);
        }
    }
    __syncthreads();   // only barrier; slab exchange below is same-wave

    const int pb = t >> 3;              // point slot (0..31)
    const int g  = t & 7;               // seed group
    const int s0 = g * 4;
    const int p  = blockIdx.x * PPB + pb;
    if (p >= N) return;

    const float4 su4  = *(const float4*)&s_su[s0];
    const float4 sv4  = *(const float4*)&s_sv[s0];
    const float4 m004 = *(const float4*)&s_m00[s0];
    const float4 m014 = *(const float4*)&s_m01[s0];
    const float4 m114 = *(const float4*)&s_m11[s0];

    const float2 uv = ((const float2*)points)[p];
    const float u = uv.x, v = uv.y;

    const float EPS_Q = 1e-8f * TSCALE * TSCALE;
    float4 d4;
#define DIST(SU, SV, M00, M01, M11, OUTD)                                  \
    {                                                                      \
        float du = u - (SU); du -= rintf(du);                              \
        float dv = v - (SV); dv -= rintf(dv);                              \
        float q = fmaf(du * du, (M00),                                     \
                  fmaf(du * dv, (M01),                                     \
                  fmaf(dv * dv, (M11), EPS_Q)));                           \
        (OUTD) = sqrtf(q);                                                 \
    }
    DIST(su4.x, sv4.x, m004.x, m014.x, m114.x, d4.x)
    DIST(su4.y, sv4.y, m004.y, m014.y, m114.y, d4.y)
    DIST(su4.z, sv4.z, m004.z, m014.z, m114.z, d4.z)
    DIST(su4.w, sv4.w, m004.w, m014.w, m114.w, d4.w)

    // softmax over 32 seeds (exponents bounded below ~ -29; no max-sub)
    const float cE = -(20.0f * LOG2E) / TSCALE;
    float4 e4;
    e4.x = exp2f(d4.x * cE);
    e4.y = exp2f(d4.y * cE);
    e4.z = exp2f(d4.z * cE);
    e4.w = exp2f(d4.w * cE);
    float Z = (e4.x + e4.y) + (e4.z + e4.w);
    Z += __shfl_xor(Z, 1, 64);
    Z += __shfl_xor(Z, 2, 64);
    Z += __shfl_xor(Z, 4, 64);
    const float rcpZ = __builtin_amdgcn_rcpf(Z);
    float4 w4;
    w4.x = e4.x * rcpZ; w4.y = e4.y * rcpZ;
    w4.z = e4.z * rcpZ; w4.w = e4.w * rcpZ;
    float sumsq = w4.x * w4.x;
    sumsq = fmaf(w4.y, w4.y, sumsq);
    sumsq = fmaf(w4.z, w4.z, sumsq);
    sumsq = fmaf(w4.w, w4.w, sumsq);

    // stage (d,w) to this point's slab row (same-wave exchange, no barrier)
    float* db = &s_dd[pb * SSTR];
    float* wb = &s_ww[pb * SSTR];
    *(float4*)(db + s0) = d4;
    *(float4*)(wb + s0) = w4;

    const char* tb = (const char*)s_tab;

    // table pair: 5 VALU + 1 ds_read_b32
#define TBODY(DI, DJ, WJ, ACC)                                             \
    {                                                                      \
        const float ad = fabsf((DI) - (DJ));                               \
        int off = ((int)(ad + 0.5f)) << 2;                                 \
        off = off < KB4 ? off : KB4;                                       \
        const float B = *(const float*)(tb + off);                         \
        (ACC) = fmaf((WJ), B, (ACC));                                      \
    }
    // exp pair: ~3 VALU + 2 trans
    const float C1 = (50.0f * LOG2E) / TSCALE;
    const float C0 = -w * (50.0f * LOG2E);
#define EBODY(DI, DJ, WJ, ACC)                                             \
    {                                                                      \
        const float ex = exp2f(fmaf(fabsf((DI) - (DJ)), C1, C0));          \
        const float B  = __builtin_amdgcn_rcpf(1.0f + ex);                 \
        (ACC) = fmaf((WJ), B, (ACC));                                      \
    }

    float b0, b1, b2, b3;
    // 6 in-lane pairs (table)
    b0 =      0.0f; b1 = 0.0f; b2 = 0.0f; b3 = 0.0f;
    TBODY(d4.x, d4.y, w4.y, b0)
    TBODY(d4.x, d4.z, w4.z, b0)
    TBODY(d4.x, d4.w, w4.w, b0)
    TBODY(d4.y, d4.z, w4.z, b1)
    TBODY(d4.y, d4.w, w4.w, b1)
    TBODY(d4.z, d4.w, w4.w, b2)

#define ROT(R, HALF, PAIR)                                                 \
    {                                                                      \
        const int gj = ((g + (R)) & 7) * 4;                                \
        const float4 dj = *(const float4*)(db + gj);                       \
        float4 wj = *(const float4*)(wb + gj);                             \
        if (HALF) { wj.x *= 0.5f; wj.y *= 0.5f; wj.z *= 0.5f; wj.w *= 0.5f; } \
        PAIR(d4.x, dj.x, wj.x, b0) PAIR(d4.x, dj.y, wj.y, b0)              \
        PAIR(d4.x, dj.z, wj.z, b0) PAIR(d4.x, dj.w, wj.w, b0)              \
        PAIR(d4.y, dj.x, wj.x, b1) PAIR(d4.y, dj.y, wj.y, b1)              \
        PAIR(d4.y, dj.z, wj.z, b1) PAIR(d4.y, dj.w, wj.w, b1)              \
        PAIR(d4.z, dj.x, wj.x, b2) PAIR(d4.z, dj.y, wj.y, b2)              \
        PAIR(d4.z, dj.z, wj.z, b2) PAIR(d4.z, dj.w, wj.w, b2)              \
        PAIR(d4.w, dj.x, wj.x, b3) PAIR(d4.w, dj.y, wj.y, b3)              \
        PAIR(d4.w, dj.z, wj.z, b3) PAIR(d4.w, dj.w, wj.w, b3)              \
    }
    ROT(1, 0, TBODY)     // 16 pairs on the DS pipe
    ROT(2, 0, EBODY)     // 32 pairs on the trans pipe
    ROT(3, 0, EBODY)
    ROT(4, 1, EBODY)     // opposite group counted twice -> half weight

    float accb = w4.x * b0;
    accb = fmaf(w4.y, b1, accb);
    accb = fmaf(w4.z, b2, accb);
    accb = fmaf(w4.w, b3, accb);

    // reduce over the point's 8 lanes
    float nb = accb, sq = sumsq;
    nb += __shfl_xor(nb, 1, 64);  sq += __shfl_xor(sq, 1, 64);
    nb += __shfl_xor(nb, 2, 64);  sq += __shfl_xor(sq, 2, 64);
    nb += __shfl_xor(nb, 4, 64);  sq += __shfl_xor(sq, 4, 64);

    // pair mass: sum_{i<j} w_i w_j = (1 - sum w^2)/2
    const float den   = fmaxf(0.5f * (1.0f - sq), 0.0f) + EPSF;
    const float ratio = nb * __builtin_amdgcn_rcpf(den);
    const float rho   = 1.0f - exp2f(ratio * (-8.0f * LOG2E));
    if (g == 0) out[p] = rho;
}

extern "C" void kernel_launch(void* const* d_in, const int* in_sizes, int n_in,
                              void* d_out, int out_size, void* d_ws, size_t ws_size,
                              hipStream_t stream) {
    const float* points = (const float*)d_in[0];
    const float* seeds  = (const float*)d_in[1];
    const float* w_raw  = (const float*)d_in[2];
    const float* theta  = (const float*)d_in[3];
    const float* a_raw  = (const float*)d_in[4];
    float* out = (float*)d_out;

    const int N = in_sizes[0] / 2;              // 65536
    const int grid = (N + PPB - 1) / PPB;       // 2048 blocks, 1 tile each

    voronoi_v6<<<grid, BLOCK, 0, stream>>>(points, seeds, w_raw, theta, a_raw,
                                           out, N);
}

// Round 7
// 16.493 us; speedup vs baseline: 1.2631x; 1.2631x over previous
//
#include <hip/hip_runtime.h>
#include <math.h>

// VoronoiDecoder: N=65536 x S=32. 8 lanes/point, 4 seeds/lane, 512-thr blocks,
// 64 points/block, grid=1024 (exactly 4 blocks/CU). All 70 pair-sigmoids per
// thread via LDS table with SATURATION CLAMP: indices med3-clamped to the
// sigmoid transition zone [T1,T2], so far/near pairs read broadcast addresses
// (conflict-free); only transition-zone lanes scatter. launch_bounds(512,8)
// pins VGPR<=64 so all 4 blocks/CU are resident (8 waves/SIMD).

#define LOG2E  1.4426950408889634f
#define EPSF   1e-8f
#define TSC    4096.0f          // distance units per 1.0
#define TAB_N  2816             // covers T2max = 0.5*4096+750 = 2798
#define HBAND  750              // 9.15 * BETA * TSC : |sigma| tail < 1.1e-4
#define BLOCK  512
#define PPB    64               // points per block
#define SSTR   40               // slab row stride (words): 2-way banks = free

__global__ __launch_bounds__(BLOCK, 8) void voronoi_v7(
    const float* __restrict__ points,   // (N,2)
    const float* __restrict__ seeds,    // (32,2)
    const float* __restrict__ w_raw,    // (1,)
    const float* __restrict__ theta,    // (32,)
    const float* __restrict__ a_raw,    // (32,)
    float* __restrict__ out,            // (N,)
    int N)
{
    __shared__ float    s_tab[TAB_N];
    __shared__ unsigned s_ii[PPB * SSTR];
    __shared__ float    s_ww[PPB * SSTR];
    __shared__ float    s_su[32], s_sv[32], s_m00[32], s_m01[32], s_m11[32];

    const int t = threadIdx.x;

    // uniform band half-width (SGPR math)
    const float wr = w_raw[0];
    const float sg = __builtin_amdgcn_rcpf(1.0f + exp2f(wr * (-LOG2E / 5.0f)));
    const float w  = 0.005f + 0.495f * sg;

    // saturation clamp window in table BYTE offsets
    const int icent = (int)(w * TSC + 0.5f);
    const int T1B   = (icent > HBAND ? icent - HBAND : 0) << 2;
    const int T2B   = (icent + HBAND) << 2;          // <= 2798*4 < TAB_N*4

    // seed metrics, pre-scaled so sqrt lands in table units (2x folded in m01)
    if (t < 32) {
        const float x  = a_raw[t];
        const float z  = exp2f(2.0f * LOG2E * x);
        const float th = (z - 1.0f) * __builtin_amdgcn_rcpf(z + 1.0f);  // tanh
        const float a  = 0.75f * th + 1.25f;
        const float ia = __builtin_amdgcn_rcpf(a + EPSF);
        const float cs = __cosf(theta[t]);
        const float sn = __sinf(theta[t]);
        const float S2 = TSC * TSC;
        s_m00[t] = (a * cs * cs + ia * sn * sn) * S2;
        s_m01[t] = (2.0f * cs * sn * (ia - a)) * S2;
        s_m11[t] = (a * sn * sn + ia * cs * cs) * S2;
        s_su[t]  = seeds[2 * t];
        s_sv[t]  = seeds[2 * t + 1];
    }
    // band table: T[k] = sigmoid((w - k/TSC)/0.02)
    {
        const float kC = (50.0f * LOG2E) / TSC;
        const float kB = -w * (50.0f * LOG2E);
        #pragma unroll
        for (int k = t; k < TAB_N; k += BLOCK) {
            const float y = exp2f(fmaf((float)k, kC, kB));
            s_tab[k] = __builtin_amdgcn_rcpf(1.0f + y);
        }
    }
    __syncthreads();   // only barrier; slab exchange below is same-wave

    const int pb = t >> 3;              // point slot (0..63)
    const int g  = t & 7;               // seed group
    const int s0 = g * 4;
    const int p  = blockIdx.x * PPB + pb;
    if (p >= N) return;

    const float4 su4  = *(const float4*)&s_su[s0];
    const float4 sv4  = *(const float4*)&s_sv[s0];
    const float4 m004 = *(const float4*)&s_m00[s0];
    const float4 m014 = *(const float4*)&s_m01[s0];
    const float4 m114 = *(const float4*)&s_m11[s0];

    const float2 uv = ((const float2*)points)[p];
    const float u = uv.x, v = uv.y;

    const float EPS_Q = 1e-8f * TSC * TSC;
    float4 d4;
#define DIST(SU, SV, M00, M01, M11, OUTD)                                  \
    {                                                                      \
        float du = u - (SU); du -= rintf(du);                              \
        float dv = v - (SV); dv -= rintf(dv);                              \
        float q = fmaf(du * du, (M00),                                     \
                  fmaf(du * dv, (M01),                                     \
                  fmaf(dv * dv, (M11), EPS_Q)));                           \
        (OUTD) = sqrtf(q);                                                 \
    }
    DIST(su4.x, sv4.x, m004.x, m014.x, m114.x, d4.x)
    DIST(su4.y, sv4.y, m004.y, m014.y, m114.y, d4.y)
    DIST(su4.z, sv4.z, m004.z, m014.z, m114.z, d4.z)
    DIST(su4.w, sv4.w, m004.w, m014.w, m114.w, d4.w)

    // softmax over 32 seeds (exponents bounded below ~ -29; no max-sub)
    const float cE = -(20.0f * LOG2E) / TSC;
    float4 e4;
    e4.x = exp2f(d4.x * cE);
    e4.y = exp2f(d4.y * cE);
    e4.z = exp2f(d4.z * cE);
    e4.w = exp2f(d4.w * cE);
    float Z = (e4.x + e4.y) + (e4.z + e4.w);
    Z += __shfl_xor(Z, 1, 64);
    Z += __shfl_xor(Z, 2, 64);
    Z += __shfl_xor(Z, 4, 64);
    const float rcpZ = __builtin_amdgcn_rcpf(Z);
    float4 w4;
    w4.x = e4.x * rcpZ; w4.y = e4.y * rcpZ;
    w4.z = e4.z * rcpZ; w4.w = e4.w * rcpZ;
    float sumsq = w4.x * w4.x;
    sumsq = fmaf(w4.y, w4.y, sumsq);
    sumsq = fmaf(w4.z, w4.z, sumsq);
    sumsq = fmaf(w4.w, w4.w, sumsq);

    // quantize d to byte offsets (round-to-nearest)
    uint4 ii;
    ii.x = ((unsigned)(d4.x + 0.5f)) << 2;
    ii.y = ((unsigned)(d4.y + 0.5f)) << 2;
    ii.z = ((unsigned)(d4.z + 0.5f)) << 2;
    ii.w = ((unsigned)(d4.w + 0.5f)) << 2;

    // stage to this point's slab row (same-wave exchange, no barrier)
    unsigned* db = &s_ii[pb * SSTR];
    float*    wb = &s_ww[pb * SSTR];
    *(uint4*) (db + s0) = ii;
    *(float4*)(wb + s0) = w4;

    const char* tb = (const char*)s_tab;

    // pair: max,min,sub + clamp-to-transition (tails -> broadcast addr) + read
#define TBODY(IA, IB, WJ, ACC)                                             \
    {                                                                      \
        const unsigned hi = (IA) > (IB) ? (IA) : (IB);                     \
        const unsigned lo = (IA) > (IB) ? (IB) : (IA);                     \
        int diff = (int)(hi - lo);                                         \
        diff = diff > T1B ? diff : T1B;                                    \
        diff = diff < T2B ? diff : T2B;                                    \
        const float B = *(const float*)(tb + diff);                        \
        (ACC) = fmaf((WJ), B, (ACC));                                      \
    }

    // 6 in-lane pairs
    float b0, b1, b2, b3;
    b0 = 0.0f; b1 = 0.0f; b2 = 0.0f; b3 = 0.0f;
    TBODY(ii.x, ii.y, w4.y, b0)
    TBODY(ii.x, ii.z, w4.z, b0)
    TBODY(ii.x, ii.w, w4.w, b0)
    TBODY(ii.y, ii.z, w4.z, b1)
    TBODY(ii.y, ii.w, w4.w, b1)
    TBODY(ii.z, ii.w, w4.w, b2)

#define ROT(R)                                                             \
    {                                                                      \
        const int gj = ((g + (R)) & 7) * 4;                                \
        const uint4  ij = *(const uint4*) (db + gj);                       \
        const float4 wj = *(const float4*)(wb + gj);                       \
        TBODY(ii.x, ij.x, wj.x, b0)                                        \
        TBODY(ii.x, ij.y, wj.y, b0)                                        \
        TBODY(ii.x, ij.z, wj.z, b0)                                        \
        TBODY(ii.x, ij.w, wj.w, b0)                                        \
        TBODY(ii.y, ij.x, wj.x, b1)                                        \
        TBODY(ii.y, ij.y, wj.y, b1)                                        \
        TBODY(ii.y, ij.z, wj.z, b1)                                        \
        TBODY(ii.y, ij.w, wj.w, b1)                                        \
        TBODY(ii.z, ij.x, wj.x, b2)                                        \
        TBODY(ii.z, ij.y, wj.y, b2)                                        \
        TBODY(ii.z, ij.z, wj.z, b2)                                        \
        TBODY(ii.z, ij.w, wj.w, b2)                                        \
        TBODY(ii.w, ij.x, wj.x, b3)                                        \
        TBODY(ii.w, ij.y, wj.y, b3)                                        \
        TBODY(ii.w, ij.z, wj.z, b3)                                        \
        TBODY(ii.w, ij.w, wj.w, b3)                                        \
    }
    ROT(1)
    ROT(2)
    ROT(3)
    if (g < 4) {        // r=4 at full weight on half the lanes (no redundancy)
        ROT(4)
    }

    float accb = w4.x * b0;
    accb = fmaf(w4.y, b1, accb);
    accb = fmaf(w4.z, b2, accb);
    accb = fmaf(w4.w, b3, accb);

    // reduce over the point's 8 lanes
    float nb = accb, sq = sumsq;
    nb += __shfl_xor(nb, 1, 64);  sq += __shfl_xor(sq, 1, 64);
    nb += __shfl_xor(nb, 2, 64);  sq += __shfl_xor(sq, 2, 64);
    nb += __shfl_xor(nb, 4, 64);  sq += __shfl_xor(sq, 4, 64);

    // pair mass: sum_{i<j} w_i w_j = (1 - sum w^2)/2
    const float den   = fmaxf(0.5f * (1.0f - sq), 0.0f) + EPSF;
    const float ratio = nb * __builtin_amdgcn_rcpf(den);
    const float rho   = 1.0f - exp2f(ratio * (-8.0f * LOG2E));
    if (g == 0) out[p] = rho;
}

extern "C" void kernel_launch(void* const* d_in, const int* in_sizes, int n_in,
                              void* d_out, int out_size, void* d_ws, size_t ws_size,
                              hipStream_t stream) {
    const float* points = (const float*)d_in[0];
    const float* seeds  = (const float*)d_in[1];
    const float* w_raw  = (const float*)d_in[2];
    const float* theta  = (const float*)d_in[3];
    const float* a_raw  = (const float*)d_in[4];
    float* out = (float*)d_out;

    const int N = in_sizes[0] / 2;              // 65536
    const int grid = (N + PPB - 1) / PPB;       // 1024 blocks = 4/CU exact

    voronoi_v7<<<grid, BLOCK, 0, stream>>>(points, seeds, w_raw, theta, a_raw,
                                           out, N);
}